// Round 5
// baseline (478.959 us; speedup 1.0000x reference)
//
#include <hip/hip_runtime.h>

#define NT 512
#define ROWLEN 16384
#define PT 8      // u32x4 per thread in k1: 8 * 4 * 512 = 16384 floats
#define CAP 4096  // candidate buffer entries (16 KB)

typedef unsigned int u32x4 __attribute__((ext_vector_type(4)));

__device__ inline unsigned mbcnt64(unsigned long long m) {
  unsigned lo = __builtin_amdgcn_mbcnt_lo((unsigned)m, 0u);
  return __builtin_amdgcn_mbcnt_hi((unsigned)(m >> 32), lo);
}

// Descending (suffix) bin selection over NB bins with NT threads.
// Finds bin b with count(bins > b) < krem <= count(bins >= b).
// sel[0] = b, sel[1] = krem - count(bins > b).
template<int NB>
__device__ inline void select_bin(unsigned* hist, unsigned* wtot,
                                  unsigned* sel, unsigned tid, unsigned krem) {
  constexpr int BPT = NB / NT;
  constexpr int NW = NT / 64;
  const unsigned base = tid * BPT;
  unsigned c[BPT];
  unsigned s = 0;
#pragma unroll
  for (int i = 0; i < BPT; i++) { c[i] = hist[base + i]; s += c[i]; }

  const unsigned lane = tid & 63u;
  const unsigned wid  = tid >> 6;

  // inclusive suffix sum within the wave (sum over lanes >= lane)
  unsigned suf = s;
#pragma unroll
  for (int off = 1; off < 64; off <<= 1) {
    unsigned v = __shfl_down(suf, off);
    if (lane + off < 64) suf += v;
  }
  if (lane == 0) wtot[wid] = suf;
  __syncthreads();

  unsigned above = suf - s;  // elements in higher bins within this wave
  for (unsigned w = wid + 1; w < NW; w++) above += wtot[w];

#pragma unroll
  for (int i = BPT - 1; i >= 0; i--) {
    unsigned cc = c[i];
    if (above < krem && above + cc >= krem) {
      sel[0] = base + (unsigned)i;
      sel[1] = krem - above;
    }
    above += cc;
  }
  __syncthreads();
}

// ---- kernel 1: per-row exact k-th-largest |x| threshold (bit pattern, a-space) ----
__global__ __launch_bounds__(NT, 5)
void topk_thresh_kernel(const float* __restrict__ x, unsigned* __restrict__ thresh,
                        const int* __restrict__ kp) {
  __shared__ unsigned hist1[2048];
  __shared__ unsigned hist2[1024];
  __shared__ unsigned hist3[1024];
  __shared__ unsigned cand[CAP];
  __shared__ unsigned wtot[NT / 64];
  __shared__ unsigned sel[2];
  __shared__ unsigned cnt;

  const unsigned tid = threadIdx.x;
  const unsigned k = (unsigned)*kp;
  const size_t rowoff = (size_t)blockIdx.x * (size_t)ROWLEN;
  const u32x4* __restrict__ xr = reinterpret_cast<const u32x4*>(x + rowoff);

  // coalesced TEMPORAL load (we want x resident in L3 for kernel 2)
  u32x4 d[PT];
#pragma unroll
  for (int j = 0; j < PT; j++) d[j] = xr[tid + j * NT];

  // zero everything up front (overlaps with loads in flight)
#pragma unroll
  for (int i = 0; i < 2048 / NT; i++) hist1[tid + i * NT] = 0u;
#pragma unroll
  for (int i = 0; i < 1024 / NT; i++) hist2[tid + i * NT] = 0u;
#pragma unroll
  for (int i = 0; i < 1024 / NT; i++) hist3[tid + i * NT] = 0u;
  if (tid == 0) cnt = 0u;
  __syncthreads();

  // ---- level 1: 2048 bins over a>>21, where a = u<<1 (sign dropped) ----
#pragma unroll
  for (int j = 0; j < PT; j++) {
    atomicAdd(&hist1[(d[j].x << 1) >> 21], 1u);
    atomicAdd(&hist1[(d[j].y << 1) >> 21], 1u);
    atomicAdd(&hist1[(d[j].z << 1) >> 21], 1u);
    atomicAdd(&hist1[(d[j].w << 1) >> 21], 1u);
  }
  __syncthreads();
  select_bin<2048>(hist1, wtot, sel, tid, k);
  const unsigned P1 = sel[0];
  const unsigned r1 = sel[1];

  // ---- gather candidates (wave-aggregated atomics) ----
  {
    auto push = [&](unsigned a) {
      bool p = (a >> 21) == P1;
      unsigned long long m = __ballot(p);
      if (m) {
        unsigned nw = (unsigned)__popcll(m);
        if (p) {
          unsigned pre = mbcnt64(m);
          unsigned b = 0;
          if (pre == 0) b = atomicAdd(&cnt, nw);
          b = __builtin_amdgcn_readfirstlane(b);
          unsigned i = b + pre;
          if (i < CAP) cand[i] = a;
        }
      }
    };
#pragma unroll
    for (int j = 0; j < PT; j++) {
      push(d[j].x << 1); push(d[j].y << 1); push(d[j].z << 1); push(d[j].w << 1);
    }
  }
  __syncthreads();
  const unsigned n = cnt;

  // ---- level 2: bins over bits (a>>11)&0x3FF ----
  if (n <= CAP) {
    for (unsigned i = tid; i < n; i += NT)
      atomicAdd(&hist2[(cand[i] >> 11) & 0x3FFu], 1u);
  } else {  // overflow fallback: full register scan
#pragma unroll
    for (int j = 0; j < PT; j++) {
      unsigned a;
      a = d[j].x << 1; if ((a >> 21) == P1) atomicAdd(&hist2[(a >> 11) & 0x3FFu], 1u);
      a = d[j].y << 1; if ((a >> 21) == P1) atomicAdd(&hist2[(a >> 11) & 0x3FFu], 1u);
      a = d[j].z << 1; if ((a >> 21) == P1) atomicAdd(&hist2[(a >> 11) & 0x3FFu], 1u);
      a = d[j].w << 1; if ((a >> 21) == P1) atomicAdd(&hist2[(a >> 11) & 0x3FFu], 1u);
    }
  }
  __syncthreads();
  select_bin<1024>(hist2, wtot, sel, tid, r1);
  const unsigned P2 = sel[0];
  const unsigned r2 = sel[1];

  // ---- level 3: bins over bits (a>>1)&0x3FF ----
  if (n <= CAP) {
    for (unsigned i = tid; i < n; i += NT) {
      unsigned a = cand[i];
      if (((a >> 11) & 0x3FFu) == P2) atomicAdd(&hist3[(a >> 1) & 0x3FFu], 1u);
    }
  } else {
    const unsigned P12 = (P1 << 10) | P2;
#pragma unroll
    for (int j = 0; j < PT; j++) {
      unsigned a;
      a = d[j].x << 1; if ((a >> 11) == P12) atomicAdd(&hist3[(a >> 1) & 0x3FFu], 1u);
      a = d[j].y << 1; if ((a >> 11) == P12) atomicAdd(&hist3[(a >> 1) & 0x3FFu], 1u);
      a = d[j].z << 1; if ((a >> 11) == P12) atomicAdd(&hist3[(a >> 1) & 0x3FFu], 1u);
      a = d[j].w << 1; if ((a >> 11) == P12) atomicAdd(&hist3[(a >> 1) & 0x3FFu], 1u);
    }
  }
  __syncthreads();
  select_bin<1024>(hist3, wtot, sel, tid, r2);

  if (tid == 0) thresh[blockIdx.x] = (P1 << 21) | (P2 << 11) | (sel[0] << 1);
}

// ---- kernel 2: streaming mask apply. x is L3-hot from kernel 1. ----
__global__ __launch_bounds__(NT)
void topk_apply_kernel(const float* __restrict__ x, const unsigned* __restrict__ thresh,
                       float* __restrict__ out) {
  const unsigned row  = blockIdx.x >> 1;
  const unsigned half = blockIdx.x & 1;
  const size_t base = (size_t)row * (size_t)ROWLEN + (size_t)half * (ROWLEN / 2);
  const unsigned Va = thresh[row];
  const u32x4* __restrict__ xr = reinterpret_cast<const u32x4*>(x + base);
  u32x4* __restrict__ orow     = reinterpret_cast<u32x4*>(out + base);
#pragma unroll
  for (int j = 0; j < 4; j++) {
    u32x4 v = xr[threadIdx.x + j * NT];
    u32x4 o;
    o.x = ((v.x << 1) >= Va) ? v.x : 0u;
    o.y = ((v.y << 1) >= Va) ? v.y : 0u;
    o.z = ((v.z << 1) >= Va) ? v.z : 0u;
    o.w = ((v.w << 1) >= Va) ? v.w : 0u;
    __builtin_nontemporal_store(o, &orow[threadIdx.x + j * NT]);  // don't evict x from L3
  }
}

extern "C" void kernel_launch(void* const* d_in, const int* in_sizes, int n_in,
                              void* d_out, int out_size, void* d_ws, size_t ws_size,
                              hipStream_t stream) {
  const float* x   = (const float*)d_in[0];
  const int*   kp  = (const int*)d_in[1];
  float*       out = (float*)d_out;
  unsigned*    thr = (unsigned*)d_ws;
  const int rows = out_size / ROWLEN;  // 4096
  topk_thresh_kernel<<<rows, NT, 0, stream>>>(x, thr, kp);
  topk_apply_kernel<<<rows * 2, NT, 0, stream>>>(x, thr, out);
}

// Round 6
// 464.845 us; speedup vs baseline: 1.0304x; 1.0304x over previous
//
#include <hip/hip_runtime.h>

#define NT 512
#define ROWLEN 16384
#define PT 8      // u32x4 per thread: 8 * 4 * 512 = 16384 floats per row
#define CAP 4096  // candidate buffer entries (16 KB)
#define RPB 4     // rows per block (software pipeline depth 2, A/B ping-pong)

typedef unsigned int u32x4 __attribute__((ext_vector_type(4)));

// Barrier that drains ONLY LDS ops (lgkmcnt), NOT vmem (vmcnt) — keeps
// prefetch loads / output stores in flight across the hist/select phases.
// __syncthreads() would emit s_waitcnt vmcnt(0) (workgroup acq_rel fence).
__device__ inline void sync_lds() {
  asm volatile("s_waitcnt lgkmcnt(0)" ::: "memory");
  __builtin_amdgcn_s_barrier();
  asm volatile("" ::: "memory");
}

__device__ inline unsigned mbcnt64(unsigned long long m) {
  unsigned lo = __builtin_amdgcn_mbcnt_lo((unsigned)m, 0u);
  return __builtin_amdgcn_mbcnt_hi((unsigned)(m >> 32), lo);
}

// Descending (suffix) bin selection over NB bins with NT threads.
// Finds bin b with count(bins > b) < krem <= count(bins >= b).
// sel[0] = b, sel[1] = krem - count(bins > b).
template<int NB>
__device__ inline void select_bin(unsigned* hist, unsigned* wtot,
                                  unsigned* sel, unsigned tid, unsigned krem) {
  constexpr int BPT = NB / NT;
  constexpr int NW = NT / 64;
  const unsigned base = tid * BPT;
  unsigned c[BPT];
  unsigned s = 0;
#pragma unroll
  for (int i = 0; i < BPT; i++) { c[i] = hist[base + i]; s += c[i]; }

  const unsigned lane = tid & 63u;
  const unsigned wid  = tid >> 6;

  // inclusive suffix sum within the wave (sum over lanes >= lane)
  unsigned suf = s;
#pragma unroll
  for (int off = 1; off < 64; off <<= 1) {
    unsigned v = __shfl_down(suf, off);
    if (lane + off < 64) suf += v;
  }
  if (lane == 0) wtot[wid] = suf;
  sync_lds();

  unsigned above = suf - s;  // elements in higher bins within this wave
  for (unsigned w = wid + 1; w < NW; w++) above += wtot[w];

#pragma unroll
  for (int i = BPT - 1; i >= 0; i--) {
    unsigned cc = c[i];
    if (above < krem && above + cc >= krem) {
      sel[0] = base + (unsigned)i;
      sel[1] = krem - above;
    }
    above += cc;
  }
  sync_lds();
}

__global__ __launch_bounds__(NT, 4)
void topk_act_kernel(const float* __restrict__ x, float* __restrict__ out,
                     const int* __restrict__ kp) {
  __shared__ unsigned hist1[2048];
  __shared__ unsigned hist2[1024];
  __shared__ unsigned hist3[1024];
  __shared__ unsigned cand[CAP];
  __shared__ unsigned wtot[NT / 64];
  __shared__ unsigned sel[2];
  __shared__ unsigned cnt;

  const unsigned tid = threadIdx.x;
  const unsigned k = (unsigned)*kp;
  const size_t row0 = (size_t)blockIdx.x * RPB;

  u32x4 dA[PT], dB[PT];

  auto load_row = [&](u32x4 (&d)[PT], unsigned r) {
    const u32x4* __restrict__ xr =
        reinterpret_cast<const u32x4*>(x + (row0 + r) * (size_t)ROWLEN);
#pragma unroll
    for (int j = 0; j < PT; j++) d[j] = xr[tid + j * NT];
  };

  auto process = [&](u32x4 (&d)[PT], unsigned r) {
    // ---- zero all histograms (one barrier covers everything) ----
#pragma unroll
    for (int i = 0; i < 2048 / NT; i++) hist1[tid + i * NT] = 0u;
#pragma unroll
    for (int i = 0; i < 1024 / NT; i++) { hist2[tid + i * NT] = 0u; hist3[tid + i * NT] = 0u; }
    if (tid == 0) cnt = 0u;
    sync_lds();

    // ---- level 1: 2048 bins over a>>21, a = u<<1 (sign dropped) ----
#pragma unroll
    for (int j = 0; j < PT; j++) {
      atomicAdd(&hist1[(d[j].x << 1) >> 21], 1u);
      atomicAdd(&hist1[(d[j].y << 1) >> 21], 1u);
      atomicAdd(&hist1[(d[j].z << 1) >> 21], 1u);
      atomicAdd(&hist1[(d[j].w << 1) >> 21], 1u);
    }
    sync_lds();
    select_bin<2048>(hist1, wtot, sel, tid, k);
    const unsigned P1 = sel[0];
    const unsigned r1 = sel[1];

    // ---- gather candidates (wave-aggregated atomics) ----
    {
      auto push = [&](unsigned a) {
        bool p = (a >> 21) == P1;
        unsigned long long m = __ballot(p);
        if (m) {
          unsigned nw = (unsigned)__popcll(m);
          if (p) {
            unsigned pre = mbcnt64(m);
            unsigned b = 0;
            if (pre == 0) b = atomicAdd(&cnt, nw);
            b = __builtin_amdgcn_readfirstlane(b);
            unsigned i = b + pre;
            if (i < CAP) cand[i] = a;
          }
        }
      };
#pragma unroll
      for (int j = 0; j < PT; j++) {
        push(d[j].x << 1); push(d[j].y << 1); push(d[j].z << 1); push(d[j].w << 1);
      }
    }
    sync_lds();
    const unsigned n = cnt;

    // ---- level 2: bins over (a>>11)&0x3FF ----
    if (n <= CAP) {
      for (unsigned i = tid; i < n; i += NT)
        atomicAdd(&hist2[(cand[i] >> 11) & 0x3FFu], 1u);
    } else {  // overflow fallback: full register scan
#pragma unroll
      for (int j = 0; j < PT; j++) {
        unsigned a;
        a = d[j].x << 1; if ((a >> 21) == P1) atomicAdd(&hist2[(a >> 11) & 0x3FFu], 1u);
        a = d[j].y << 1; if ((a >> 21) == P1) atomicAdd(&hist2[(a >> 11) & 0x3FFu], 1u);
        a = d[j].z << 1; if ((a >> 21) == P1) atomicAdd(&hist2[(a >> 11) & 0x3FFu], 1u);
        a = d[j].w << 1; if ((a >> 21) == P1) atomicAdd(&hist2[(a >> 11) & 0x3FFu], 1u);
      }
    }
    sync_lds();
    select_bin<1024>(hist2, wtot, sel, tid, r1);
    const unsigned P2 = sel[0];
    const unsigned r2 = sel[1];

    // ---- level 3: bins over (a>>1)&0x3FF ----
    if (n <= CAP) {
      for (unsigned i = tid; i < n; i += NT) {
        unsigned a = cand[i];
        if (((a >> 11) & 0x3FFu) == P2) atomicAdd(&hist3[(a >> 1) & 0x3FFu], 1u);
      }
    } else {
      const unsigned P12 = (P1 << 10) | P2;
#pragma unroll
      for (int j = 0; j < PT; j++) {
        unsigned a;
        a = d[j].x << 1; if ((a >> 11) == P12) atomicAdd(&hist3[(a >> 1) & 0x3FFu], 1u);
        a = d[j].y << 1; if ((a >> 11) == P12) atomicAdd(&hist3[(a >> 1) & 0x3FFu], 1u);
        a = d[j].z << 1; if ((a >> 11) == P12) atomicAdd(&hist3[(a >> 1) & 0x3FFu], 1u);
        a = d[j].w << 1; if ((a >> 11) == P12) atomicAdd(&hist3[(a >> 1) & 0x3FFu], 1u);
      }
    }
    sync_lds();
    select_bin<1024>(hist3, wtot, sel, tid, r2);
    const unsigned Va = (P1 << 21) | (P2 << 11) | (sel[0] << 1);  // k-th largest, a-space

    // ---- mask and nontemporal write (stays in flight across next row) ----
    u32x4* __restrict__ orow =
        reinterpret_cast<u32x4*>(out + (row0 + r) * (size_t)ROWLEN);
#pragma unroll
    for (int j = 0; j < PT; j++) {
      u32x4 v = d[j];
      u32x4 o;
      o.x = ((v.x << 1) >= Va) ? v.x : 0u;
      o.y = ((v.y << 1) >= Va) ? v.y : 0u;
      o.z = ((v.z << 1) >= Va) ? v.z : 0u;
      o.w = ((v.w << 1) >= Va) ? v.w : 0u;
      __builtin_nontemporal_store(o, &orow[tid + j * NT]);
    }
  };

  // software pipeline: prefetch next row while processing current
  load_row(dA, 0);
  load_row(dB, 1);
  process(dA, 0);
  load_row(dA, 2);
  process(dB, 1);
  load_row(dB, 3);
  process(dA, 2);
  process(dB, 3);
}

extern "C" void kernel_launch(void* const* d_in, const int* in_sizes, int n_in,
                              void* d_out, int out_size, void* d_ws, size_t ws_size,
                              hipStream_t stream) {
  const float* x   = (const float*)d_in[0];
  const int*   kp  = (const int*)d_in[1];
  float*       out = (float*)d_out;
  const int rows = out_size / ROWLEN;  // 4096
  topk_act_kernel<<<rows / RPB, NT, 0, stream>>>(x, out, kp);
}